// Round 7
// baseline (185.345 us; speedup 1.0000x reference)
//
#include <hip/hip_runtime.h>

// YOLOv7 P3 head (stride 8): B=16, A=3, NC=80, H=W=80.
// Input  (b, a*85, h, w) channel-major fp32.
// Output (b, a*h*w, 85)  fp32: [px,py,pw,ph,conf,cls*80].
//
// v8: y-QUAD blocks -> 1280B read segments (cross the ~1-2KB DRAM page /
// interleave granule). Evidence: v1-v7 pinned at 2.35-2.65 TB/s for ~153MB
// compulsory DRAM traffic; same-capture fillBuffer ran 6.6 TB/s @ 9% occ
// (so no chip ceiling); refuted: store policy, MLP, barriers, occupancy,
// segments 320->640B. Last untested lever: read segments above the DRAM
// page granule. Block = (ba, y/4): 960 blocks, 1024 threads, LDS 108.8KB
// (1 block/CU, 16 waves). 85 channel segments x 1280B contiguous reads;
// 54.4KB contiguous cached stores.

#define A_     3
#define H_     80
#define W_     80
#define CH_    85                    // 5 + 80 classes
#define HW_    (H_ * W_)             // 6400
#define YR_    4                     // y rows per block
#define TILEF_ (CH_ * W_ * YR_)      // 27200 floats
#define QT_    (TILEF_ / 4)          // 6800 f32x4 quads
#define NIT_   7                     // ceil(6800 / 1024)

typedef float f32x4 __attribute__((ext_vector_type(4)));

__device__ __forceinline__ float fast_sigmoid(float x) {
    return __builtin_amdgcn_rcpf(1.0f + __expf(-x));
}

__global__ __launch_bounds__(1024) void yolo_head_kernel(
    const float* __restrict__ in,
    const float* __restrict__ anchors,
    float* __restrict__ out)
{
    __shared__ float lds[TILEF_];   // 108800 B

    const int bid = blockIdx.x;         // ba*20 + y4
    const int y4  = bid % (H_ / YR_);
    const int ba  = bid / (H_ / YR_);   // b*3 + a
    const int a   = ba % A_;
    const int y0  = y4 * YR_;

    const float aw = anchors[2 * a];
    const float ah = anchors[2 * a + 1];
    const int   t  = threadIdx.x;

    // ---- Phase 1a: 7 clamped f32x4 loads, 1280B segments ----
    // quad i = ch*80 + xq, xq in [0,80): 320 floats = rows y0..y0+3 of ch.
    const float* in_base = in + (size_t)(ba * CH_) * HW_ + y0 * W_;

    f32x4 v[NIT_];
#pragma unroll
    for (int k = 0; k < NIT_; ++k) {
        int i = k * 1024 + t;
        i = (i < QT_) ? i : (QT_ - 1);   // clamp: tail lanes re-load last quad
        int ch = i / 80;
        int xq = i - ch * 80;
        v[k] = *(const f32x4*)(in_base + ch * HW_ + 4 * xq);
    }
    __builtin_amdgcn_sched_barrier(0);

    // ---- Phase 1b: transform -> LDS transposed [4 rows][80 x][85 ch] ----
#pragma unroll
    for (int k = 0; k < NIT_; ++k) {
        int i = k * 1024 + t;
        if (i < QT_) {
            int ch = i / 80;
            int xq = i - ch * 80;
            int r  = xq / 20;                // row within y-quad (quads don't straddle)
            int xb = 4 * xq - 80 * r;        // x of elem j: xb + j
            f32x4 d = v[k];
            float rr[4];
            if (ch >= 4) {
                rr[0] = fast_sigmoid(d.x);
                rr[1] = fast_sigmoid(d.y);
                rr[2] = fast_sigmoid(d.z);
                rr[3] = fast_sigmoid(d.w);
            } else if (ch == 0) {
                float xg = (float)xb;
                rr[0] = (fast_sigmoid(d.x) + xg)        * 8.0f;  // px
                rr[1] = (fast_sigmoid(d.y) + xg + 1.0f) * 8.0f;
                rr[2] = (fast_sigmoid(d.z) + xg + 2.0f) * 8.0f;
                rr[3] = (fast_sigmoid(d.w) + xg + 3.0f) * 8.0f;
            } else if (ch == 1) {
                float fy = (float)(y0 + r);
                rr[0] = (fast_sigmoid(d.x) + fy) * 8.0f;         // py
                rr[1] = (fast_sigmoid(d.y) + fy) * 8.0f;
                rr[2] = (fast_sigmoid(d.z) + fy) * 8.0f;
                rr[3] = (fast_sigmoid(d.w) + fy) * 8.0f;
            } else {
                float s = (ch == 2) ? aw : ah;                   // pw / ph
                rr[0] = __expf(fminf(fmaxf(d.x, -16.0f), 16.0f)) * s;
                rr[1] = __expf(fminf(fmaxf(d.y, -16.0f), 16.0f)) * s;
                rr[2] = __expf(fminf(fmaxf(d.z, -16.0f), 16.0f)) * s;
                rr[3] = __expf(fminf(fmaxf(d.w, -16.0f), 16.0f)) * s;
            }
            // lds[(r*80 + xb + j)*85 + ch]
            int base = r * (CH_ * W_) + xb * CH_ + ch;
#pragma unroll
            for (int j = 0; j < 4; ++j)
                lds[base + j * CH_] = rr[j];
        }
    }
    __syncthreads();

    // ---- Phase 2: contiguous LDS read -> 54.4KB contiguous cached stores ----
    // out base: (ba*6400 + y0*80) * 85 floats; 27200 floats contiguous.
    f32x4*       out4 = (f32x4*)(out + (size_t)(ba * HW_ + y0 * W_) * CH_);
    const f32x4* lds4 = (const f32x4*)lds;

    f32x4 o[NIT_];
#pragma unroll
    for (int k = 0; k < NIT_; ++k) {
        int c = k * 1024 + t;
        c = (c < QT_) ? c : (QT_ - 1);
        o[k] = lds4[c];
    }
    __builtin_amdgcn_sched_barrier(0);
#pragma unroll
    for (int k = 0; k < NIT_; ++k) {
        int c = k * 1024 + t;
        if (c < QT_) {
            out4[c] = o[k];
        }
    }
}

extern "C" void kernel_launch(void* const* d_in, const int* in_sizes, int n_in,
                              void* d_out, int out_size, void* d_ws, size_t ws_size,
                              hipStream_t stream) {
    const float* in      = (const float*)d_in[0];   // (16, 255, 80, 80) fp32
    const float* anchors = (const float*)d_in[1];   // (3, 2) fp32
    float*       out     = (float*)d_out;           // (16, 19200, 85) fp32

    const int blocks = 16 * A_ * (H_ / YR_);        // 960: one per (b,a,y-quad)
    yolo_head_kernel<<<blocks, 1024, 0, stream>>>(in, anchors, out);
}